// Round 3
// baseline (618.028 us; speedup 1.0000x reference)
//
#include <hip/hip_runtime.h>
#include <hip/hip_bf16.h>
#include <stdint.h>

#define B_SZ 32
#define S_SZ 4096
#define H_SZ 512
#define U_SZ 512

typedef __attribute__((ext_vector_type(8))) _Float16 half8;
typedef __attribute__((ext_vector_type(4))) float floatx4;

// ---------------------------------------------------------------------------
// prep: W2 fp32 [k][n] -> W2s f16 frag-major [kb][kq][n][8]  (k = kb*32+kq*8+kk)
//       + zero qpb2 and ctx (atomicAdd targets)
// ---------------------------------------------------------------------------
__global__ __launch_bounds__(256) void prep_kernel(
    const float* __restrict__ W2, _Float16* __restrict__ W2s,
    float* __restrict__ qpb2, float* __restrict__ ctx)
{
    const int t = threadIdx.x;
    const int bid = blockIdx.x;
    const int i = bid * 256 + t;          // 0..262143
    const int k = i >> 9, n = i & 511;
    W2s[(k >> 5) * 16384 + ((k >> 3) & 3) * 4096 + n * 8 + (k & 7)] =
        (_Float16)W2[i];
    if (bid < 64) qpb2[i] = 0.0f;
    else if (bid < 128) ctx[(bid - 64) * 256 + t] = 0.0f;
}

// ---------------------------------------------------------------------------
// qproj: k-split 8, 4-way ILP.  qpb2[b][u] += partial + (b1+b2 on ks==0)
// ---------------------------------------------------------------------------
__global__ __launch_bounds__(256) void qproj_kernel(
    const float* __restrict__ query, const float* __restrict__ W1,
    const float* __restrict__ b1, const float* __restrict__ b2,
    float* __restrict__ qpb2)
{
    const int b = blockIdx.x, uc = blockIdx.y, ks = blockIdx.z;  // (32,2,8)
    const int u = uc * 256 + threadIdx.x;
    const float* q  = query + b * H_SZ + ks * 64;
    const float* Wp = W1 + (size_t)(ks * 64) * U_SZ + u;
    float a0 = 0.f, a1 = 0.f, a2 = 0.f, a3 = 0.f;
    for (int k = 0; k < 64; k += 4) {
        a0 = fmaf(q[k],     Wp[(size_t)k * U_SZ],       a0);
        a1 = fmaf(q[k + 1], Wp[(size_t)(k + 1) * U_SZ], a1);
        a2 = fmaf(q[k + 2], Wp[(size_t)(k + 2) * U_SZ], a2);
        a3 = fmaf(q[k + 3], Wp[(size_t)(k + 3) * U_SZ], a3);
    }
    float acc = (a0 + a1) + (a2 + a3);
    if (ks == 0) acc += b1[u] + b2[u];
    atomicAdd(&qpb2[b * U_SZ + u], acc);
}

// ---------------------------------------------------------------------------
// scores v3: NO barriers / NO LDS in the K-loop.
// Block 256 thr = 4 waves; wave w owns 64 m-rows x n-range [w*128,(w+1)*128).
// B frags read straight from L2-resident W2s (coalesced 16B/lane);
// A frags from values, software-pipelined one K-step ahead; acc in VGPRs.
// K-loop: 16 steps of BK=32, 32 MFMAs (16x16x32_f16) per wave per step.
// ---------------------------------------------------------------------------
__global__ __launch_bounds__(256, 2) void scores_kernel(
    const float* __restrict__ values, const _Float16* __restrict__ W2s,
    const float* __restrict__ qpb2, const float* __restrict__ va,
    const float* __restrict__ bva, float* __restrict__ scores)
{
    __shared__ float red[256];            // 64 rows x 4 waves

    const int t  = threadIdx.x;
    const int w  = t >> 6;
    const int l  = t & 63;
    const int c  = l & 15;                // n (or m) within 16-tile
    const int g4 = l >> 4;                // k-quad 0..3
    const int m0 = blockIdx.x * 64;
    const int b  = m0 >> 12;

    floatx4 acc[4][8];
#pragma unroll
    for (int mt = 0; mt < 4; ++mt)
#pragma unroll
        for (int nt = 0; nt < 8; ++nt) acc[mt][nt] = (floatx4)(0.0f);

    // per-lane base pointers
    const float* Ab = values + (size_t)(m0 + c) * H_SZ + g4 * 8;
    const _Float16* Bb = W2s + g4 * 4096 + (w * 128 + c) * 8;

    // prologue: A for kb=0
    float4 an0[4], an1[4];
#pragma unroll
    for (int mt = 0; mt < 4; ++mt) {
        const float* ap = Ab + (size_t)(mt * 16) * H_SZ;
        an0[mt] = *(const float4*)(ap);
        an1[mt] = *(const float4*)(ap + 4);
    }
    half8 af[4];
#pragma unroll
    for (int mt = 0; mt < 4; ++mt) {
        half8 a;
        a[0] = (_Float16)an0[mt].x; a[1] = (_Float16)an0[mt].y;
        a[2] = (_Float16)an0[mt].z; a[3] = (_Float16)an0[mt].w;
        a[4] = (_Float16)an1[mt].x; a[5] = (_Float16)an1[mt].y;
        a[6] = (_Float16)an1[mt].z; a[7] = (_Float16)an1[mt].w;
        af[mt] = a;
    }

    for (int kb = 0; kb < 16; ++kb) {
        // B frags for this step (L2 hits; nt-ordered so MFMA waits stagger)
        half8 bf[8];
        const _Float16* Bp = Bb + kb * 16384;
#pragma unroll
        for (int nt = 0; nt < 8; ++nt)
            bf[nt] = *(const half8*)(Bp + nt * 128);
        // A loads for next step (consumed after the MFMAs below)
        if (kb < 15) {
#pragma unroll
            for (int mt = 0; mt < 4; ++mt) {
                const float* ap = Ab + (size_t)(mt * 16) * H_SZ + (kb + 1) * 32;
                an0[mt] = *(const float4*)(ap);
                an1[mt] = *(const float4*)(ap + 4);
            }
        }
#pragma unroll
        for (int nt = 0; nt < 8; ++nt)
#pragma unroll
            for (int mt = 0; mt < 4; ++mt)
                acc[mt][nt] = __builtin_amdgcn_mfma_f32_16x16x32_f16(
                    af[mt], bf[nt], acc[mt][nt], 0, 0, 0);
        // convert next-step A (hides the A-load latency behind the MFMAs)
        if (kb < 15) {
#pragma unroll
            for (int mt = 0; mt < 4; ++mt) {
                half8 a;
                a[0] = (_Float16)an0[mt].x; a[1] = (_Float16)an0[mt].y;
                a[2] = (_Float16)an0[mt].z; a[3] = (_Float16)an0[mt].w;
                a[4] = (_Float16)an1[mt].x; a[5] = (_Float16)an1[mt].y;
                a[6] = (_Float16)an1[mt].z; a[7] = (_Float16)an1[mt].w;
                af[mt] = a;
            }
        }
    }

    // ---- epilogue: score[m] = bva + sum_n tanh(vproj+qpb2[n])*va[n] ----
    float qv2[8], vv[8], vv2[8];
#pragma unroll
    for (int nt = 0; nt < 8; ++nt) {
        const int n = w * 128 + nt * 16 + c;
        const float q = qpb2[b * U_SZ + n];
        const float v = va[n];
        qv2[nt] = 2.0f * q;
        vv[nt] = v;
        vv2[nt] = 2.0f * v;
    }
#pragma unroll
    for (int mt = 0; mt < 4; ++mt) {
#pragma unroll
        for (int r = 0; r < 4; ++r) {
            float p = 0.0f;
#pragma unroll
            for (int nt = 0; nt < 8; ++nt) {
                const float ex = __expf(fmaf(acc[mt][nt][r], 2.0f, qv2[nt]));
                const float rc = __builtin_amdgcn_rcpf(ex + 1.0f);
                p = fmaf(-vv2[nt], rc, p + vv[nt]);   // += tanh(x)*va
            }
            p += __shfl_xor(p, 1);
            p += __shfl_xor(p, 2);
            p += __shfl_xor(p, 4);
            p += __shfl_xor(p, 8);
            if (c == 0) red[(mt * 16 + g4 * 4 + r) * 4 + w] = p;
        }
    }
    __syncthreads();
    if (t < 64)
        scores[m0 + t] = *bva + red[t * 4 + 0] + red[t * 4 + 1] +
                         red[t * 4 + 2] + red[t * 4 + 3];
}

// ---------------------------------------------------------------------------
// sredux: per-batch softmax stats (max M, denom L)
// ---------------------------------------------------------------------------
__global__ __launch_bounds__(1024) void sredux_kernel(
    const float* __restrict__ scores, float* __restrict__ ML)
{
    __shared__ float red[16];
    __shared__ float s_max;
    const int b = blockIdx.x;
    const int t = threadIdx.x;
    float4 v = *(const float4*)(scores + b * S_SZ + t * 4);
    float m = fmaxf(fmaxf(v.x, v.y), fmaxf(v.z, v.w));
#pragma unroll
    for (int o = 32; o > 0; o >>= 1) m = fmaxf(m, __shfl_xor(m, o));
    if ((t & 63) == 0) red[t >> 6] = m;
    __syncthreads();
    if (t == 0) {
        float mm = red[0];
        for (int i = 1; i < 16; ++i) mm = fmaxf(mm, red[i]);
        s_max = mm;
    }
    __syncthreads();
    const float mm = s_max;
    float s = __expf(v.x - mm) + __expf(v.y - mm) +
              __expf(v.z - mm) + __expf(v.w - mm);
#pragma unroll
    for (int o = 32; o > 0; o >>= 1) s += __shfl_xor(s, o);
    if ((t & 63) == 0) red[t >> 6] = s;
    __syncthreads();
    if (t == 0) {
        float ss = 0.0f;
        for (int i = 0; i < 16; ++i) ss += red[i];
        ML[b * 2] = mm;
        ML[b * 2 + 1] = ss;
    }
}

// ---------------------------------------------------------------------------
// context v3: grid (32 ss, 2 hc, 32 b) = 2048 blocks; block = 128 s x 256 h.
// 4 independent accumulators -> 8+ loads in flight per thread.
// ---------------------------------------------------------------------------
__global__ __launch_bounds__(256) void context_kernel(
    const float* __restrict__ values, const float* __restrict__ scores,
    const float* __restrict__ ML, float* __restrict__ out)
{
    __shared__ float wl[128];
    __shared__ __align__(16) float part[4][64][4];
    const int ss = blockIdx.x, hc = blockIdx.y, b = blockIdx.z;
    const int t = threadIdx.x;
    const float M = ML[b * 2];
    const float rL = 1.0f / ML[b * 2 + 1];
    if (t < 32) {
        float4 sv = *(const float4*)(scores + b * S_SZ + ss * 128 + t * 4);
        float4 wv;
        wv.x = __expf(sv.x - M) * rL; wv.y = __expf(sv.y - M) * rL;
        wv.z = __expf(sv.z - M) * rL; wv.w = __expf(sv.w - M) * rL;
        *(float4*)&wl[t * 4] = wv;
        if (hc == 0)
            *(float4*)(out + b * S_SZ + ss * 128 + t * 4) = wv;
    }
    __syncthreads();

    const int l = t & 63, g = t >> 6;
    const float* vp = values + ((size_t)b * S_SZ + ss * 128 + g * 32) * H_SZ +
                      hc * 256 + l * 4;
    float4 a0 = {0,0,0,0}, a1 = {0,0,0,0}, a2 = {0,0,0,0}, a3 = {0,0,0,0};
    for (int i = 0; i < 32; i += 4) {
        const float w0 = wl[g * 32 + i];
        const float w1 = wl[g * 32 + i + 1];
        const float w2 = wl[g * 32 + i + 2];
        const float w3 = wl[g * 32 + i + 3];
        float4 v0 = *(const float4*)(vp + (size_t)(i)     * H_SZ);
        float4 v1 = *(const float4*)(vp + (size_t)(i + 1) * H_SZ);
        float4 v2 = *(const float4*)(vp + (size_t)(i + 2) * H_SZ);
        float4 v3 = *(const float4*)(vp + (size_t)(i + 3) * H_SZ);
        a0.x = fmaf(w0, v0.x, a0.x); a0.y = fmaf(w0, v0.y, a0.y);
        a0.z = fmaf(w0, v0.z, a0.z); a0.w = fmaf(w0, v0.w, a0.w);
        a1.x = fmaf(w1, v1.x, a1.x); a1.y = fmaf(w1, v1.y, a1.y);
        a1.z = fmaf(w1, v1.z, a1.z); a1.w = fmaf(w1, v1.w, a1.w);
        a2.x = fmaf(w2, v2.x, a2.x); a2.y = fmaf(w2, v2.y, a2.y);
        a2.z = fmaf(w2, v2.z, a2.z); a2.w = fmaf(w2, v2.w, a2.w);
        a3.x = fmaf(w3, v3.x, a3.x); a3.y = fmaf(w3, v3.y, a3.y);
        a3.z = fmaf(w3, v3.z, a3.z); a3.w = fmaf(w3, v3.w, a3.w);
    }
    a0.x += a1.x + a2.x + a3.x; a0.y += a1.y + a2.y + a3.y;
    a0.z += a1.z + a2.z + a3.z; a0.w += a1.w + a2.w + a3.w;
    *(float4*)&part[g][l][0] = a0;
    __syncthreads();
    if (t < 64) {
        float4 sa = *(float4*)&part[0][t][0];
#pragma unroll
        for (int gg = 1; gg < 4; ++gg) {
            float4 p = *(float4*)&part[gg][t][0];
            sa.x += p.x; sa.y += p.y; sa.z += p.z; sa.w += p.w;
        }
        float* ctx = out + B_SZ * S_SZ;
        const int hh = hc * 256 + t * 4;
        atomicAdd(&ctx[b * H_SZ + hh + 0], sa.x);
        atomicAdd(&ctx[b * H_SZ + hh + 1], sa.y);
        atomicAdd(&ctx[b * H_SZ + hh + 2], sa.z);
        atomicAdd(&ctx[b * H_SZ + hh + 3], sa.w);
    }
}

// ---------------------------------------------------------------------------
extern "C" void kernel_launch(void* const* d_in, const int* in_sizes, int n_in,
                              void* d_out, int out_size, void* d_ws, size_t ws_size,
                              hipStream_t stream) {
    const float* query  = (const float*)d_in[0];
    const float* values = (const float*)d_in[1];
    const float* W1     = (const float*)d_in[2];
    const float* b1     = (const float*)d_in[3];
    const float* W2     = (const float*)d_in[4];
    const float* b2     = (const float*)d_in[5];
    const float* va     = (const float*)d_in[6];
    const float* bva    = (const float*)d_in[7];
    float* out = (float*)d_out;   // [32*4096 weights][32*512 context]

    char* ws = (char*)d_ws;
    float*    qpb2   = (float*)ws;                                  // 64 KB
    _Float16* W2s    = (_Float16*)(ws + 65536);                     // 512 KB
    float*    scores = (float*)(ws + 65536 + 524288);               // 512 KB
    float*    ML     = (float*)(ws + 65536 + 524288 + 524288);      // 256 B

    float* ctx = out + B_SZ * S_SZ;

    prep_kernel<<<1024, 256, 0, stream>>>(W2, W2s, qpb2, ctx);
    qproj_kernel<<<dim3(32, 2, 8), 256, 0, stream>>>(query, W1, b1, b2, qpb2);
    scores_kernel<<<2048, 256, 0, stream>>>(values, W2s, qpb2, va, bva, scores);
    sredux_kernel<<<32, 1024, 0, stream>>>(scores, ML);
    context_kernel<<<dim3(32, 2, 32), 256, 0, stream>>>(values, scores, ML, out);
}

// Round 4
// 595.903 us; speedup vs baseline: 1.0371x; 1.0371x over previous
//
#include <hip/hip_runtime.h>
#include <hip/hip_bf16.h>
#include <stdint.h>

#define B_SZ 32
#define S_SZ 4096
#define H_SZ 512
#define U_SZ 512

typedef __attribute__((ext_vector_type(8))) _Float16 half8;
typedef __attribute__((ext_vector_type(4))) float floatx4;

__device__ __forceinline__ void async_copy16(const void* g, void* l) {
    __builtin_amdgcn_global_load_lds(
        (const __attribute__((address_space(1))) void*)g,
        (__attribute__((address_space(3))) void*)l, 16, 0, 0);
}

// ---------------------------------------------------------------------------
// prep (fused): blocks 0..1023   : W2 fp32 -> W2s f16 [kb][kq][n][8]
//               blocks 1024..1535: scores[i] = bva  (atomicAdd target)
//               blocks 1536..1599: ctx = 0          (atomicAdd target)
//               blocks 1600..1663: qproj: qpb2[b][u] = q·W1 + b1 + b2
// ---------------------------------------------------------------------------
__global__ __launch_bounds__(256) void prep_kernel(
    const float* __restrict__ W2, const float* __restrict__ b1,
    const float* __restrict__ b2, const float* __restrict__ bva,
    const float* __restrict__ query, const float* __restrict__ W1,
    _Float16* __restrict__ W2s, float* __restrict__ qpb2,
    float* __restrict__ scores, float* __restrict__ ctx)
{
    const int t = threadIdx.x;
    const int bid = blockIdx.x;
    if (bid < 1024) {
        const int i = bid * 256 + t;
        const int k = i >> 9, n = i & 511;
        W2s[(k >> 5) * 16384 + ((k >> 3) & 3) * 4096 + n * 8 + (k & 7)] =
            (_Float16)W2[i];
    } else if (bid < 1536) {
        scores[(bid - 1024) * 256 + t] = *bva;
    } else if (bid < 1600) {
        ctx[(bid - 1536) * 256 + t] = 0.0f;
    } else {
        const int bq = bid - 1600;
        const int b = bq >> 1, uc = bq & 1;
        const int u = uc * 256 + t;
        const float* q  = query + b * H_SZ;
        const float* Wp = W1 + u;
        float a0 = 0.f, a1 = 0.f, a2 = 0.f, a3 = 0.f;
        for (int k = 0; k < 512; k += 4) {
            a0 = fmaf(q[k],     Wp[(size_t)k * U_SZ],       a0);
            a1 = fmaf(q[k + 1], Wp[(size_t)(k + 1) * U_SZ], a1);
            a2 = fmaf(q[k + 2], Wp[(size_t)(k + 2) * U_SZ], a2);
            a3 = fmaf(q[k + 3], Wp[(size_t)(k + 3) * U_SZ], a3);
        }
        qpb2[b * U_SZ + u] = (a0 + a1) + (a2 + a3) + b1[u] + b2[u];
    }
}

// ---------------------------------------------------------------------------
// scores v4 (m97-style): 128x128 tile, BK=32, 16 steps, 1 barrier/step.
// Both operands staged via global_load_lds(16B) into double-buffered LDS:
//   A: raw fp32, LDS chunk j = g*128 + ml  (g = k-group of 4 floats)
//   B: f16 from pre-swizzled W2s, chunk j = kq*128 + nl
// Wave w: m-half mh=w>>1, n-half nh=w&1 -> 4x4 tiles of 16x16, 16 MFMA/step.
// Epilogue: partial score over this block's 128 n -> 1 atomicAdd per row.
// Grid: 4096 = 1024 m-tiles x 4 n-tiles, n fastest (A-tile L3 reuse).
// ---------------------------------------------------------------------------
__global__ __launch_bounds__(256, 3) void scores_kernel(
    const float* __restrict__ values, const _Float16* __restrict__ W2s,
    const float* __restrict__ qpb2, const float* __restrict__ va,
    float* __restrict__ scores)
{
    __shared__ __align__(16) float    Albs[2][4096];   // 2 x 16 KB
    __shared__ __align__(16) _Float16 Blbs[2][4096];   // 2 x 8 KB
    __shared__ float red[256];

    const int t  = threadIdx.x;
    const int w  = t >> 6, l = t & 63;
    const int c  = l & 15, g4 = l >> 4;
    const int mh = w >> 1, nh = w & 1;
    const int n0 = (blockIdx.x & 3) * 128;
    const int m0 = (blockIdx.x >> 2) * 128;
    const int b  = m0 >> 12;

    floatx4 acc[4][4];
#pragma unroll
    for (int mt = 0; mt < 4; ++mt)
#pragma unroll
        for (int nt = 0; nt < 4; ++nt) acc[mt][nt] = (floatx4)(0.0f);

    const float*    Vb0 = values + (size_t)m0 * H_SZ;
    const _Float16* Wb0 = W2s + n0 * 8;

    // stage slab kb into buffer buf
    auto stage = [&](int kb, int buf) {
        const float* Vb = Vb0 + kb * 32;
#pragma unroll
        for (int i = 0; i < 4; ++i) {
            const int j = t + i * 256;              // 0..1023
            const int g = j >> 7, ml = j & 127;
            async_copy16(Vb + (size_t)ml * H_SZ + g * 4, &Albs[buf][j * 4]);
        }
        const _Float16* Wb = Wb0 + kb * 16384;
#pragma unroll
        for (int i = 0; i < 2; ++i) {
            const int j = t + i * 256;              // 0..511
            const int kq = j >> 7, nl = j & 127;
            async_copy16(Wb + kq * 4096 + nl * 8, &Blbs[buf][j * 8]);
        }
    };

    stage(0, 0);
    __syncthreads();

    for (int kb = 0; kb < 16; ++kb) {
        const int cur = kb & 1;
        if (kb < 15) stage(kb + 1, cur ^ 1);   // DMA covered by MFMA section
        // A frags: two b128 per m-tile, quarter-wave contiguous (no conflicts)
        half8 af[4];
#pragma unroll
        for (int mt = 0; mt < 4; ++mt) {
            const int ml = mh * 64 + mt * 16 + c;
            float4 lo = *(const float4*)&Albs[cur][((2 * g4)     * 128 + ml) * 4];
            float4 hi = *(const float4*)&Albs[cur][((2 * g4 + 1) * 128 + ml) * 4];
            half8 a;
            a[0] = (_Float16)lo.x; a[1] = (_Float16)lo.y;
            a[2] = (_Float16)lo.z; a[3] = (_Float16)lo.w;
            a[4] = (_Float16)hi.x; a[5] = (_Float16)hi.y;
            a[6] = (_Float16)hi.z; a[7] = (_Float16)hi.w;
            af[mt] = a;
        }
        half8 bf[4];
#pragma unroll
        for (int nt = 0; nt < 4; ++nt) {
            const int nl = nh * 64 + nt * 16 + c;
            bf[nt] = *(const half8*)&Blbs[cur][(g4 * 128 + nl) * 8];
        }
#pragma unroll
        for (int mt = 0; mt < 4; ++mt)
#pragma unroll
            for (int nt = 0; nt < 4; ++nt)
                acc[mt][nt] = __builtin_amdgcn_mfma_f32_16x16x32_f16(
                    af[mt], bf[nt], acc[mt][nt], 0, 0, 0);
        __syncthreads();
    }

    // ---- epilogue: partial over this block's 128 n-cols ----
    float qv2[4], vv[4], vv2[4];
#pragma unroll
    for (int nt = 0; nt < 4; ++nt) {
        const int n = n0 + nh * 64 + nt * 16 + c;
        const float q = qpb2[b * U_SZ + n];
        const float v = va[n];
        qv2[nt] = 2.0f * q;
        vv[nt] = v;
        vv2[nt] = 2.0f * v;
    }
#pragma unroll
    for (int mt = 0; mt < 4; ++mt) {
#pragma unroll
        for (int r = 0; r < 4; ++r) {
            float p = 0.0f;
#pragma unroll
            for (int nt = 0; nt < 4; ++nt) {
                const float ex = __expf(fmaf(acc[mt][nt][r], 2.0f, qv2[nt]));
                const float rc = __builtin_amdgcn_rcpf(ex + 1.0f);
                p = fmaf(-vv2[nt], rc, p + vv[nt]);   // += tanh(x)*va
            }
            p += __shfl_xor(p, 1);
            p += __shfl_xor(p, 2);
            p += __shfl_xor(p, 4);
            p += __shfl_xor(p, 8);
            if (c == 0)
                red[(mh * 64 + mt * 16 + g4 * 4 + r) * 2 + nh] = p;
        }
    }
    __syncthreads();
    if (t < 128)
        atomicAdd(&scores[m0 + t], red[t * 2] + red[t * 2 + 1]);
}

// ---------------------------------------------------------------------------
// sredux: per-batch softmax stats (max M, denom L)
// ---------------------------------------------------------------------------
__global__ __launch_bounds__(1024) void sredux_kernel(
    const float* __restrict__ scores, float* __restrict__ ML)
{
    __shared__ float red[16];
    __shared__ float s_max;
    const int b = blockIdx.x;
    const int t = threadIdx.x;
    float4 v = *(const float4*)(scores + b * S_SZ + t * 4);
    float m = fmaxf(fmaxf(v.x, v.y), fmaxf(v.z, v.w));
#pragma unroll
    for (int o = 32; o > 0; o >>= 1) m = fmaxf(m, __shfl_xor(m, o));
    if ((t & 63) == 0) red[t >> 6] = m;
    __syncthreads();
    if (t == 0) {
        float mm = red[0];
        for (int i = 1; i < 16; ++i) mm = fmaxf(mm, red[i]);
        s_max = mm;
    }
    __syncthreads();
    const float mm = s_max;
    float s = __expf(v.x - mm) + __expf(v.y - mm) +
              __expf(v.z - mm) + __expf(v.w - mm);
#pragma unroll
    for (int o = 32; o > 0; o >>= 1) s += __shfl_xor(s, o);
    if ((t & 63) == 0) red[t >> 6] = s;
    __syncthreads();
    if (t == 0) {
        float ss = 0.0f;
        for (int i = 0; i < 16; ++i) ss += red[i];
        ML[b * 2] = mm;
        ML[b * 2 + 1] = ss;
    }
}

// ---------------------------------------------------------------------------
// context v4: grid (32 s-chunks, 32 b).  Block: 128 s-rows x full 512 h.
// Wave g handles 32 rows; each wave-load is a contiguous 1 KB (half row).
// 4 independent acc chains -> 8 x 16B loads in flight per thread.
// Also writes the attention_weights output for its s-chunk.
// ---------------------------------------------------------------------------
__global__ __launch_bounds__(256) void context_kernel(
    const float* __restrict__ values, const float* __restrict__ scores,
    const float* __restrict__ ML, float* __restrict__ out)
{
    __shared__ float wl[128];
    __shared__ __align__(16) float part[4][512];
    const int sc = blockIdx.x, b = blockIdx.y;
    const int t = threadIdx.x;
    const int s0 = sc * 128;
    const float M = ML[b * 2];
    const float rL = 1.0f / ML[b * 2 + 1];
    if (t < 32) {
        float4 sv = *(const float4*)(scores + b * S_SZ + s0 + t * 4);
        float4 wv;
        wv.x = __expf(sv.x - M) * rL; wv.y = __expf(sv.y - M) * rL;
        wv.z = __expf(sv.z - M) * rL; wv.w = __expf(sv.w - M) * rL;
        *(float4*)&wl[t * 4] = wv;
        *(float4*)(out + b * S_SZ + s0 + t * 4) = wv;   // weights output
    }
    __syncthreads();

    const int g = t >> 6, l = t & 63;
    const float* vp = values + ((size_t)b * S_SZ + s0 + g * 32) * H_SZ + l * 4;
    float4 a00 = {0,0,0,0}, a01 = {0,0,0,0}, a10 = {0,0,0,0}, a11 = {0,0,0,0};
    for (int i = 0; i < 32; i += 2) {
        const float w0 = wl[g * 32 + i];
        const float w1 = wl[g * 32 + i + 1];
        const float* r0 = vp + (size_t)i * H_SZ;
        const float* r1 = r0 + H_SZ;
        float4 v00 = *(const float4*)(r0);
        float4 v01 = *(const float4*)(r0 + 256);
        float4 v10 = *(const float4*)(r1);
        float4 v11 = *(const float4*)(r1 + 256);
        a00.x = fmaf(w0, v00.x, a00.x); a00.y = fmaf(w0, v00.y, a00.y);
        a00.z = fmaf(w0, v00.z, a00.z); a00.w = fmaf(w0, v00.w, a00.w);
        a01.x = fmaf(w0, v01.x, a01.x); a01.y = fmaf(w0, v01.y, a01.y);
        a01.z = fmaf(w0, v01.z, a01.z); a01.w = fmaf(w0, v01.w, a01.w);
        a10.x = fmaf(w1, v10.x, a10.x); a10.y = fmaf(w1, v10.y, a10.y);
        a10.z = fmaf(w1, v10.z, a10.z); a10.w = fmaf(w1, v10.w, a10.w);
        a11.x = fmaf(w1, v11.x, a11.x); a11.y = fmaf(w1, v11.y, a11.y);
        a11.z = fmaf(w1, v11.z, a11.z); a11.w = fmaf(w1, v11.w, a11.w);
    }
    a00.x += a10.x; a00.y += a10.y; a00.z += a10.z; a00.w += a10.w;
    a01.x += a11.x; a01.y += a11.y; a01.z += a11.z; a01.w += a11.w;
    *(float4*)&part[g][l * 4] = a00;
    *(float4*)&part[g][256 + l * 4] = a01;
    __syncthreads();

    float* ctx = out + B_SZ * S_SZ;
#pragma unroll
    for (int rep = 0; rep < 2; ++rep) {
        const int h = rep * 256 + t;
        const float s = (part[0][h] + part[1][h]) + (part[2][h] + part[3][h]);
        atomicAdd(&ctx[b * H_SZ + h], s);
    }
}

// ---------------------------------------------------------------------------
extern "C" void kernel_launch(void* const* d_in, const int* in_sizes, int n_in,
                              void* d_out, int out_size, void* d_ws, size_t ws_size,
                              hipStream_t stream) {
    const float* query  = (const float*)d_in[0];
    const float* values = (const float*)d_in[1];
    const float* W1     = (const float*)d_in[2];
    const float* b1     = (const float*)d_in[3];
    const float* W2     = (const float*)d_in[4];
    const float* b2     = (const float*)d_in[5];
    const float* va     = (const float*)d_in[6];
    const float* bva    = (const float*)d_in[7];
    float* out = (float*)d_out;   // [32*4096 weights][32*512 context]

    char* ws = (char*)d_ws;
    float*    qpb2   = (float*)ws;                       // 64 KB
    _Float16* W2s    = (_Float16*)(ws + 65536);          // 512 KB
    float*    scores = (float*)(ws + 65536 + 524288);    // 512 KB
    float*    ML     = (float*)(ws + 65536 + 2 * 524288);

    float* ctx = out + B_SZ * S_SZ;

    prep_kernel<<<1664, 256, 0, stream>>>(W2, b1, b2, bva, query, W1,
                                          W2s, qpb2, scores, ctx);
    scores_kernel<<<4096, 256, 0, stream>>>(values, W2s, qpb2, va, scores);
    sredux_kernel<<<32, 1024, 0, stream>>>(scores, ML);
    context_kernel<<<dim3(32, 32), 256, 0, stream>>>(values, scores, ML, out);
}

// Round 6
// 545.868 us; speedup vs baseline: 1.1322x; 1.0917x over previous
//
#include <hip/hip_runtime.h>
#include <hip/hip_bf16.h>
#include <stdint.h>

#define B_SZ 32
#define S_SZ 4096
#define H_SZ 512
#define U_SZ 512

typedef __attribute__((ext_vector_type(8))) _Float16 half8;
typedef __attribute__((ext_vector_type(4))) float floatx4;

__device__ __forceinline__ void async_copy16(const void* g, void* l) {
    __builtin_amdgcn_global_load_lds(
        (const __attribute__((address_space(1))) void*)g,
        (__attribute__((address_space(3))) void*)l, 16, 0, 0);
}

// ---------------------------------------------------------------------------
// prep (fused):
//   blocks [0, nconv)          : values fp32 -> vf16 (row-major), 8 elem/thr
//                                nconv = 67108864/(256*8) = 32768  (FIX: was 16384)
//   rb = bid-nconv:
//     rb in [0,1024)           : W2 fp32 -> W2s f16 [kb][kq][n][8]
//     rb in [1024,1536)        : scores[i] = bva   (atomicAdd target)
//     rb in [1536,1600)        : ctx = 0           (atomicAdd target)
//     rb in [1600,1664)        : qproj: qpb2[b][u] = q·W1 + b1 + b2
// ---------------------------------------------------------------------------
__global__ __launch_bounds__(256) void prep_kernel(
    const float* __restrict__ values, const float* __restrict__ W2,
    const float* __restrict__ b1, const float* __restrict__ b2,
    const float* __restrict__ bva, const float* __restrict__ query,
    const float* __restrict__ W1, _Float16* __restrict__ W2s,
    float* __restrict__ qpb2, float* __restrict__ scores,
    float* __restrict__ ctx, _Float16* __restrict__ vf16, int nconv)
{
    const int t = threadIdx.x;
    const int bid = blockIdx.x;
    if (bid < nconv) {
        const size_t i = ((size_t)bid * 256 + t) * 8;
        float4 v0 = *(const float4*)(values + i);
        float4 v1 = *(const float4*)(values + i + 4);
        half8 h;
        h[0] = (_Float16)v0.x; h[1] = (_Float16)v0.y;
        h[2] = (_Float16)v0.z; h[3] = (_Float16)v0.w;
        h[4] = (_Float16)v1.x; h[5] = (_Float16)v1.y;
        h[6] = (_Float16)v1.z; h[7] = (_Float16)v1.w;
        *(half8*)(vf16 + i) = h;
        return;
    }
    const int rb = bid - nconv;
    if (rb < 1024) {
        const int i = rb * 256 + t;
        const int k = i >> 9, n = i & 511;
        W2s[(k >> 5) * 16384 + ((k >> 3) & 3) * 4096 + n * 8 + (k & 7)] =
            (_Float16)W2[i];
    } else if (rb < 1536) {
        scores[(rb - 1024) * 256 + t] = *bva;
    } else if (rb < 1600) {
        ctx[(rb - 1536) * 256 + t] = 0.0f;
    } else {
        const int bq = rb - 1600;
        const int b = bq >> 1, uc = bq & 1;
        const int u = uc * 256 + t;
        const float* q  = query + b * H_SZ;
        const float* Wp = W1 + u;
        float a0 = 0.f, a1 = 0.f, a2 = 0.f, a3 = 0.f;
        for (int k = 0; k < 512; k += 4) {
            a0 = fmaf(q[k],     Wp[(size_t)k * U_SZ],       a0);
            a1 = fmaf(q[k + 1], Wp[(size_t)(k + 1) * U_SZ], a1);
            a2 = fmaf(q[k + 2], Wp[(size_t)(k + 2) * U_SZ], a2);
            a3 = fmaf(q[k + 3], Wp[(size_t)(k + 3) * U_SZ], a3);
        }
        qpb2[b * U_SZ + u] = (a0 + a1) + (a2 + a3) + b1[u] + b2[u];
    }
}

// ---------------------------------------------------------------------------
// scores v5 (m97-style): 128x128 tile, BK=32, 16 steps, 1 barrier/step.
// AT = _Float16 (A = pre-converted vf16; 8 KB slabs, direct half8 frags) or
// AT = float (fallback: raw values; 16 KB slabs + per-step cvt).
// Both operands staged via global_load_lds(16B), double-buffered.
// Wave w: mh=w>>1, nh=w&1 -> 4x4 tiles of 16x16, 16 MFMA/step.
// Grid: 4096 = 1024 m-tiles x 4 n-tiles, n fastest.
// ---------------------------------------------------------------------------
template <typename AT>
__global__ __launch_bounds__(256, 4) void scores_kernel(
    const AT* __restrict__ A, const _Float16* __restrict__ W2s,
    const float* __restrict__ qpb2, const float* __restrict__ va,
    float* __restrict__ scores)
{
    __shared__ __align__(16) AT       Albs[2][4096];
    __shared__ __align__(16) _Float16 Blbs[2][4096];
    __shared__ float red[256];

    const int t  = threadIdx.x;
    const int w  = t >> 6, l = t & 63;
    const int c  = l & 15, g4 = l >> 4;
    const int mh = w >> 1, nh = w & 1;
    const int n0 = (blockIdx.x & 3) * 128;
    const int m0 = (blockIdx.x >> 2) * 128;
    const int b  = m0 >> 12;

    floatx4 acc[4][4];
#pragma unroll
    for (int mt = 0; mt < 4; ++mt)
#pragma unroll
        for (int nt = 0; nt < 4; ++nt) acc[mt][nt] = (floatx4)(0.0f);

    const AT*       Ab0 = A + (size_t)m0 * H_SZ;
    const _Float16* Wb0 = W2s + n0 * 8;

    auto stage = [&](int kb, int buf) {
        const AT* Vb = Ab0 + kb * 32;
        if constexpr (sizeof(AT) == 4) {
#pragma unroll
            for (int i = 0; i < 4; ++i) {
                const int j = t + i * 256;          // 0..1023
                const int g = j >> 7, ml = j & 127;
                async_copy16(Vb + (size_t)ml * H_SZ + g * 4, &Albs[buf][j * 4]);
            }
        } else {
#pragma unroll
            for (int i = 0; i < 2; ++i) {
                const int j = t + i * 256;          // 0..511
                const int g = j >> 7, ml = j & 127;
                async_copy16(Vb + (size_t)ml * H_SZ + g * 8, &Albs[buf][j * 8]);
            }
        }
        const _Float16* Wb = Wb0 + kb * 16384;
#pragma unroll
        for (int i = 0; i < 2; ++i) {
            const int j = t + i * 256;              // 0..511
            const int kq = j >> 7, nl = j & 127;
            async_copy16(Wb + kq * 4096 + nl * 8, &Blbs[buf][j * 8]);
        }
    };

    stage(0, 0);
    __syncthreads();

    for (int kb = 0; kb < 16; ++kb) {
        const int cur = kb & 1;
        if (kb < 15) stage(kb + 1, cur ^ 1);   // DMA lands during MFMA section
        half8 af[4];
#pragma unroll
        for (int mt = 0; mt < 4; ++mt) {
            const int ml = mh * 64 + mt * 16 + c;
            if constexpr (sizeof(AT) == 4) {
                float4 lo = *(const float4*)&Albs[cur][((2 * g4)     * 128 + ml) * 4];
                float4 hi = *(const float4*)&Albs[cur][((2 * g4 + 1) * 128 + ml) * 4];
                half8 a;
                a[0] = (_Float16)lo.x; a[1] = (_Float16)lo.y;
                a[2] = (_Float16)lo.z; a[3] = (_Float16)lo.w;
                a[4] = (_Float16)hi.x; a[5] = (_Float16)hi.y;
                a[6] = (_Float16)hi.z; a[7] = (_Float16)hi.w;
                af[mt] = a;
            } else {
                af[mt] = *(const half8*)&Albs[cur][(g4 * 128 + ml) * 8];
            }
        }
        half8 bf[4];
#pragma unroll
        for (int nt = 0; nt < 4; ++nt) {
            const int nl = nh * 64 + nt * 16 + c;
            bf[nt] = *(const half8*)&Blbs[cur][(g4 * 128 + nl) * 8];
        }
#pragma unroll
        for (int mt = 0; mt < 4; ++mt)
#pragma unroll
            for (int nt = 0; nt < 4; ++nt)
                acc[mt][nt] = __builtin_amdgcn_mfma_f32_16x16x32_f16(
                    af[mt], bf[nt], acc[mt][nt], 0, 0, 0);
        __syncthreads();
    }

    // ---- epilogue: partial over this block's 128 n-cols ----
    float qv2[4], vv[4], vv2[4];
#pragma unroll
    for (int nt = 0; nt < 4; ++nt) {
        const int n = n0 + nh * 64 + nt * 16 + c;
        const float q = qpb2[b * U_SZ + n];
        const float v = va[n];
        qv2[nt] = 2.0f * q;
        vv[nt] = v;
        vv2[nt] = 2.0f * v;
    }
#pragma unroll
    for (int mt = 0; mt < 4; ++mt) {
#pragma unroll
        for (int r = 0; r < 4; ++r) {
            float p = 0.0f;
#pragma unroll
            for (int nt = 0; nt < 4; ++nt) {
                const float ex = __expf(fmaf(acc[mt][nt][r], 2.0f, qv2[nt]));
                const float rc = __builtin_amdgcn_rcpf(ex + 1.0f);
                p = fmaf(-vv2[nt], rc, p + vv[nt]);   // += tanh(x)*va
            }
            p += __shfl_xor(p, 1);
            p += __shfl_xor(p, 2);
            p += __shfl_xor(p, 4);
            p += __shfl_xor(p, 8);
            if (c == 0)
                red[(mh * 64 + mt * 16 + g4 * 4 + r) * 2 + nh] = p;
        }
    }
    __syncthreads();
    if (t < 128)
        atomicAdd(&scores[m0 + t], red[t * 2] + red[t * 2 + 1]);
}

// ---------------------------------------------------------------------------
// sredux: per-batch softmax stats (max M, denom L)
// ---------------------------------------------------------------------------
__global__ __launch_bounds__(1024) void sredux_kernel(
    const float* __restrict__ scores, float* __restrict__ ML)
{
    __shared__ float red[16];
    __shared__ float s_max;
    const int b = blockIdx.x;
    const int t = threadIdx.x;
    float4 v = *(const float4*)(scores + b * S_SZ + t * 4);
    float m = fmaxf(fmaxf(v.x, v.y), fmaxf(v.z, v.w));
#pragma unroll
    for (int o = 32; o > 0; o >>= 1) m = fmaxf(m, __shfl_xor(m, o));
    if ((t & 63) == 0) red[t >> 6] = m;
    __syncthreads();
    if (t == 0) {
        float mm = red[0];
        for (int i = 1; i < 16; ++i) mm = fmaxf(mm, red[i]);
        s_max = mm;
    }
    __syncthreads();
    const float mm = s_max;
    float s = __expf(v.x - mm) + __expf(v.y - mm) +
              __expf(v.z - mm) + __expf(v.w - mm);
#pragma unroll
    for (int o = 32; o > 0; o >>= 1) s += __shfl_xor(s, o);
    if ((t & 63) == 0) red[t >> 6] = s;
    __syncthreads();
    if (t == 0) {
        float ss = 0.0f;
        for (int i = 0; i < 16; ++i) ss += red[i];
        ML[b * 2] = mm;
        ML[b * 2 + 1] = ss;
    }
}

// ---------------------------------------------------------------------------
// context (f16): grid (32 sc, 32 b); block 256 = 4 waves x 32 rows each.
// One full 512-h row per wave-load (64 lanes x half8 = 1 KB contiguous).
// 4 independent FMA chains; cross-wave reduce in LDS; atomicAdd to ctx.
// ---------------------------------------------------------------------------
__global__ __launch_bounds__(256) void context_f16_kernel(
    const _Float16* __restrict__ vf16, const float* __restrict__ scores,
    const float* __restrict__ ML, float* __restrict__ out)
{
    __shared__ float wl[128];
    __shared__ float part[4][512];
    const int sc = blockIdx.x, b = blockIdx.y;
    const int t = threadIdx.x;
    const int s0 = sc * 128;
    const float M = ML[b * 2];
    const float rL = 1.0f / ML[b * 2 + 1];
    if (t < 32) {
        float4 sv = *(const float4*)(scores + b * S_SZ + s0 + t * 4);
        float4 wv;
        wv.x = __expf(sv.x - M) * rL; wv.y = __expf(sv.y - M) * rL;
        wv.z = __expf(sv.z - M) * rL; wv.w = __expf(sv.w - M) * rL;
        *(float4*)&wl[t * 4] = wv;
        *(float4*)(out + b * S_SZ + s0 + t * 4) = wv;   // weights output
    }
    __syncthreads();

    const int g = t >> 6, l = t & 63;
    const _Float16* vp = vf16 + ((size_t)b * S_SZ + s0 + g * 32) * H_SZ + l * 8;
    float a[4][8];
#pragma unroll
    for (int u = 0; u < 4; ++u)
#pragma unroll
        for (int e = 0; e < 8; ++e) a[u][e] = 0.0f;
    for (int i = 0; i < 32; i += 4) {
#pragma unroll
        for (int u = 0; u < 4; ++u) {
            const float wu = wl[g * 32 + i + u];
            half8 hv = *(const half8*)(vp + (size_t)(i + u) * H_SZ);
#pragma unroll
            for (int e = 0; e < 8; ++e)
                a[u][e] = fmaf(wu, (float)hv[e], a[u][e]);
        }
    }
#pragma unroll
    for (int e = 0; e < 8; ++e)
        part[g][l * 8 + e] = (a[0][e] + a[1][e]) + (a[2][e] + a[3][e]);
    __syncthreads();

    float* ctx = out + B_SZ * S_SZ;
#pragma unroll
    for (int rep = 0; rep < 2; ++rep) {
        const int h = rep * 256 + t;
        const float s = (part[0][h] + part[1][h]) + (part[2][h] + part[3][h]);
        atomicAdd(&ctx[b * H_SZ + h], s);
    }
}

// ---------------------------------------------------------------------------
// context (fp32 fallback): R4 version
// ---------------------------------------------------------------------------
__global__ __launch_bounds__(256) void context_f32_kernel(
    const float* __restrict__ values, const float* __restrict__ scores,
    const float* __restrict__ ML, float* __restrict__ out)
{
    __shared__ float wl[128];
    __shared__ __align__(16) float part[4][512];
    const int sc = blockIdx.x, b = blockIdx.y;
    const int t = threadIdx.x;
    const int s0 = sc * 128;
    const float M = ML[b * 2];
    const float rL = 1.0f / ML[b * 2 + 1];
    if (t < 32) {
        float4 sv = *(const float4*)(scores + b * S_SZ + s0 + t * 4);
        float4 wv;
        wv.x = __expf(sv.x - M) * rL; wv.y = __expf(sv.y - M) * rL;
        wv.z = __expf(sv.z - M) * rL; wv.w = __expf(sv.w - M) * rL;
        *(float4*)&wl[t * 4] = wv;
        *(float4*)(out + b * S_SZ + s0 + t * 4) = wv;
    }
    __syncthreads();

    const int g = t >> 6, l = t & 63;
    const float* vp = values + ((size_t)b * S_SZ + s0 + g * 32) * H_SZ + l * 4;
    float4 a00 = {0,0,0,0}, a01 = {0,0,0,0}, a10 = {0,0,0,0}, a11 = {0,0,0,0};
    for (int i = 0; i < 32; i += 2) {
        const float w0 = wl[g * 32 + i];
        const float w1 = wl[g * 32 + i + 1];
        const float* r0 = vp + (size_t)i * H_SZ;
        const float* r1 = r0 + H_SZ;
        float4 v00 = *(const float4*)(r0);
        float4 v01 = *(const float4*)(r0 + 256);
        float4 v10 = *(const float4*)(r1);
        float4 v11 = *(const float4*)(r1 + 256);
        a00.x = fmaf(w0, v00.x, a00.x); a00.y = fmaf(w0, v00.y, a00.y);
        a00.z = fmaf(w0, v00.z, a00.z); a00.w = fmaf(w0, v00.w, a00.w);
        a01.x = fmaf(w0, v01.x, a01.x); a01.y = fmaf(w0, v01.y, a01.y);
        a01.z = fmaf(w0, v01.z, a01.z); a01.w = fmaf(w0, v01.w, a01.w);
        a10.x = fmaf(w1, v10.x, a10.x); a10.y = fmaf(w1, v10.y, a10.y);
        a10.z = fmaf(w1, v10.z, a10.z); a10.w = fmaf(w1, v10.w, a10.w);
        a11.x = fmaf(w1, v11.x, a11.x); a11.y = fmaf(w1, v11.y, a11.y);
        a11.z = fmaf(w1, v11.z, a11.z); a11.w = fmaf(w1, v11.w, a11.w);
    }
    a00.x += a10.x; a00.y += a10.y; a00.z += a10.z; a00.w += a10.w;
    a01.x += a11.x; a01.y += a11.y; a01.z += a11.z; a01.w += a11.w;
    *(float4*)&part[g][l * 4] = a00;
    *(float4*)&part[g][256 + l * 4] = a01;
    __syncthreads();

    float* ctx = out + B_SZ * S_SZ;
#pragma unroll
    for (int rep = 0; rep < 2; ++rep) {
        const int h = rep * 256 + t;
        const float s = (part[0][h] + part[1][h]) + (part[2][h] + part[3][h]);
        atomicAdd(&ctx[b * H_SZ + h], s);
    }
}

// ---------------------------------------------------------------------------
extern "C" void kernel_launch(void* const* d_in, const int* in_sizes, int n_in,
                              void* d_out, int out_size, void* d_ws, size_t ws_size,
                              hipStream_t stream) {
    const float* query  = (const float*)d_in[0];
    const float* values = (const float*)d_in[1];
    const float* W1     = (const float*)d_in[2];
    const float* b1     = (const float*)d_in[3];
    const float* W2     = (const float*)d_in[4];
    const float* b2     = (const float*)d_in[5];
    const float* va     = (const float*)d_in[6];
    const float* bva    = (const float*)d_in[7];
    float* out = (float*)d_out;   // [32*4096 weights][32*512 context]

    char* ws = (char*)d_ws;
    float*    qpb2   = (float*)ws;                        // 64 KB
    _Float16* W2s    = (_Float16*)(ws + 65536);           // 512 KB
    float*    scores = (float*)(ws + 589824);             // 512 KB
    float*    ML     = (float*)(ws + 1114112);            // 4 KB slot
    _Float16* vf16   = (_Float16*)(ws + 1118208);         // 128 MB (f16 path)

    const size_t NEED = 1118208ull + 134217728ull;
    const bool f16path = ws_size >= NEED;
    // values has 32*4096*512 = 67,108,864 elements; 2048 per block -> 32768
    const int nconv = f16path ? 32768 : 0;

    float* ctx = out + B_SZ * S_SZ;

    prep_kernel<<<nconv + 1664, 256, 0, stream>>>(
        values, W2, b1, b2, bva, query, W1, W2s, qpb2, scores, ctx, vf16, nconv);
    if (f16path) {
        scores_kernel<_Float16><<<4096, 256, 0, stream>>>(vf16, W2s, qpb2, va, scores);
    } else {
        scores_kernel<float><<<4096, 256, 0, stream>>>(values, W2s, qpb2, va, scores);
    }
    sredux_kernel<<<32, 1024, 0, stream>>>(scores, ML);
    if (f16path) {
        context_f16_kernel<<<dim3(32, 32), 256, 0, stream>>>(vf16, scores, ML, out);
    } else {
        context_f32_kernel<<<dim3(32, 32), 256, 0, stream>>>(values, scores, ML, out);
    }
}